// Round 7
// baseline (417.873 us; speedup 1.0000x reference)
//
#include <hip/hip_runtime.h>
#include <hip/hip_bf16.h>

#define BSz 2
#define Nn 15135
#define Ee 242160
#define F_INc 8
#define Hh 64
#define Ll 4
#define HFCc 256
#define NCc 10
#define EPSg 1e-15f
#define NBLK ((Nn + 255) / 256)   // 60 scan blocks
#define XWAVES 8192               // expand resident waves (2048 blocks x 4)

__device__ __forceinline__ float uf(unsigned u) { return __uint_as_float(u); }
__device__ __forceinline__ unsigned short bs16(float f) {
    unsigned b = __float_as_uint(f);
    return (unsigned short)((b + 0x7FFFu + ((b >> 16) & 1u)) >> 16);
}
__device__ __forceinline__ unsigned packbf(float a, float b) {
    return (unsigned)bs16(a) | ((unsigned)bs16(b) << 16);
}

// ---- CSR build ----------------------------------------------------------

__global__ void count_kernel(const int* __restrict__ dst, int* __restrict__ cnt) {
    int e = blockIdx.x * blockDim.x + threadIdx.x;
    if (e < Ee) atomicAdd(&cnt[dst[e]], 1);
}

__global__ void scan_local(const int* __restrict__ cnt, int* __restrict__ loc,
                           int* __restrict__ bsum) {
    int tid = threadIdx.x, lane = tid & 63, w = tid >> 6;
    int i = blockIdx.x * 256 + tid;
    __shared__ int ws[4];
    int v = (i < Nn) ? cnt[i] : 0;
    int incl = v;
#pragma unroll
    for (int d = 1; d < 64; d <<= 1) {
        int t = __shfl_up(incl, d, 64);
        if (lane >= d) incl += t;
    }
    if (lane == 63) ws[w] = incl;
    __syncthreads();
    int pre = 0;
    for (int ww = 0; ww < w; ++ww) pre += ws[ww];
    if (i < Nn) loc[i] = pre + incl - v;
    if (tid == 255) bsum[blockIdx.x] = pre + incl;
}

__global__ void scan_tops(int* __restrict__ bsum) {
    int lane = threadIdx.x;
    int v = (lane < NBLK) ? bsum[lane] : 0;
    int incl = v;
#pragma unroll
    for (int d = 1; d < 64; d <<= 1) {
        int t = __shfl_up(incl, d, 64);
        if (lane >= d) incl += t;
    }
    if (lane < NBLK) bsum[lane] = incl - v;
}

__global__ void scan_fix(const int* __restrict__ loc, const int* __restrict__ bsum,
                         int* __restrict__ offs, int* __restrict__ cursor) {
    int i = blockIdx.x * 256 + threadIdx.x;
    if (i < Nn) {
        int o = loc[i] + bsum[blockIdx.x];
        offs[i] = o;
        cursor[i] = o;
    }
    if (i == 0) offs[Nn] = Ee;
}

// fill CSR: src index + pseudo coords only (gauss computed in expand)
__global__ void fill_kernel(const int* __restrict__ src, const int* __restrict__ dst,
                            const float* __restrict__ pseudo, int* __restrict__ cursor,
                            int* __restrict__ csr_src, float2* __restrict__ csr_ps) {
    int e = blockIdx.x * blockDim.x + threadIdx.x;
    if (e >= Ee) return;
    int p = atomicAdd(&cursor[dst[e]], 1);
    csr_src[p] = src[e];
    csr_ps[p] = ((const float2*)pseudo)[e];
}

// ---- transform: hkp[n][h] = uint2{pack(b0k0,b1k0), pack(b0k1,b1k1)} ------
template<int F>
__global__ void transform_pack(const float* __restrict__ in, const float* __restrict__ g,
                               uint2* __restrict__ hkp) {
    int tid = threadIdx.x;
    int h = tid & 63;
    int r = tid >> 6;
    int n0 = blockIdx.x * 4;
    int n = n0 + r;
    __shared__ float s_in[4][2][F];
    for (int idx = tid; idx < 4 * 2 * F; idx += 256) {
        int rr = idx / (2 * F);
        int bb = (idx / F) & 1;
        int ff = idx % F;
        int gn = n0 + rr;
        s_in[rr][bb][ff] = (gn < Nn) ? in[((size_t)bb * Nn + gn) * F + ff] : 0.f;
    }
    __syncthreads();
    if (n >= Nn) return;
    float a00 = 0.f, a01 = 0.f, a10 = 0.f, a11 = 0.f;  // a{batch}{k}
#pragma unroll
    for (int f = 0; f < F; ++f) {
        float G0 = g[f * 128 + h];
        float G1 = g[f * 128 + 64 + h];
        float v0 = s_in[r][0][f];
        float v1 = s_in[r][1][f];
        a00 = fmaf(v0, G0, a00);
        a01 = fmaf(v0, G1, a01);
        a10 = fmaf(v1, G0, a10);
        a11 = fmaf(v1, G1, a11);
    }
    hkp[(size_t)n * 64 + h] = make_uint2(packbf(a00, a10), packbf(a01, a11));
}

// ---- expand: wave per edge, CSR order. msg[p][lane] = packed {m_b0, m_b1} -
__global__ void expand_kernel(const uint2* __restrict__ hkp, const int* __restrict__ csr_src,
                              const float2* __restrict__ csr_ps, const float* __restrict__ mu,
                              const float* __restrict__ sg, unsigned* __restrict__ msg) {
    int lane = threadIdx.x & 63;
    int wave = blockIdx.x * (blockDim.x >> 6) + (threadIdx.x >> 6);
    float m0 = mu[0], m1 = mu[1], m2 = mu[2], m3 = mu[3];
    float i0 = 1.f / (EPSg + sg[0] * sg[0]);
    float i1 = 1.f / (EPSg + sg[1] * sg[1]);
    float i2 = 1.f / (EPSg + sg[2] * sg[2]);
    float i3 = 1.f / (EPSg + sg[3] * sg[3]);
    const int per = (Ee + XWAVES - 1) / XWAVES;
    int e0 = wave * per;
    int e1 = e0 + per < Ee ? e0 + per : Ee;
#pragma unroll 2
    for (int p = e0; p < e1; ++p) {
        int srow = csr_src[p];
        float2 ps = csr_ps[p];
        float d00 = ps.x - m0, d01 = ps.y - m1;
        float d10 = ps.x - m2, d11 = ps.y - m3;
        float g0 = expf(-0.5f * (d00 * d00 * i0 + d01 * d01 * i1));
        float g1 = expf(-0.5f * (d10 * d10 * i2 + d11 * d11 * i3));
        uint2 u = hkp[(size_t)srow * 64 + lane];
        float a0 = g0 * uf(u.x << 16) + g1 * uf(u.y << 16);
        float a1 = g0 * uf(u.x & 0xFFFF0000u) + g1 * uf(u.y & 0xFFFF0000u);
        msg[(size_t)p * 64 + lane] = packbf(a0, a1);
    }
}

// ---- seg_combine: wave per node; contiguous msg read + R5 epilogue -------
template<int F>
__global__ void seg_combine(const unsigned* __restrict__ msg, const int* __restrict__ offs,
                            const float* __restrict__ prev, const float* __restrict__ root,
                            const float* __restrict__ bias, const float* __restrict__ fc_w,
                            int l, float* __restrict__ hout, float* __restrict__ node) {
    int tid = threadIdx.x;
    int lane = tid & 63;
    int n = blockIdx.x * 16 + (tid >> 6);
    if (n >= Nn) return;
    int s0 = offs[n], s1 = offs[n + 1];
    float acc0 = 0.f, acc1 = 0.f;
    int p = s0;
    for (; p + 3 < s1; p += 4) {
        unsigned ua = msg[(size_t)p * 64 + lane];
        unsigned ub = msg[(size_t)(p + 1) * 64 + lane];
        unsigned uc = msg[(size_t)(p + 2) * 64 + lane];
        unsigned ud = msg[(size_t)(p + 3) * 64 + lane];
        acc0 += uf(ua << 16) + uf(ub << 16) + uf(uc << 16) + uf(ud << 16);
        acc1 += uf(ua & 0xFFFF0000u) + uf(ub & 0xFFFF0000u)
              + uf(uc & 0xFFFF0000u) + uf(ud & 0xFFFF0000u);
    }
    for (; p < s1; ++p) {
        unsigned ua = msg[(size_t)p * 64 + lane];
        acc0 += uf(ua << 16);
        acc1 += uf(ua & 0xFFFF0000u);
    }
    float dg = (float)(s1 - s0);
    if (dg < 1.f) dg = 1.f;
    float inv = 1.f / dg;
    float bv = bias[lane];
    float fw = fc_w[lane * Ll + l];
#pragma unroll
    for (int b = 0; b < BSz; ++b) {
        size_t row = (size_t)b * Nn + n;
        float val = (b == 0 ? acc0 : acc1) * inv;
        float rsum = 0.f;
#pragma unroll
        for (int f = 0; f < F; ++f) rsum += prev[row * F + f] * root[f * 64 + lane];
        val += rsum + bv;
        val = val > 0.f ? val : expm1f(val);
        hout[row * 64 + lane] = val;
        float r = val * fw;
#pragma unroll
        for (int off = 32; off; off >>= 1) r += __shfl_down(r, off, 64);
        if (lane == 0) node[row] = (l == 0) ? r : node[row] + r;
    }
}

// ---- head ----------------------------------------------------------------

__global__ void lin1_kernel(const float* __restrict__ node, const float* __restrict__ w,
                            const float* __restrict__ fcb, float* __restrict__ h1acc) {
    int hfc = threadIdx.x;
    int n0 = blockIdx.x * 64;
    int nend = n0 + 64 < Nn ? n0 + 64 : Nn;
    float fb = fcb[0];
    float a0 = 0.f, a1 = 0.f;
    for (int n = n0; n < nend; ++n) {
        float wv = w[(size_t)n * HFCc + hfc];
        a0 += (node[n] + fb) * wv;
        a1 += (node[Nn + n] + fb) * wv;
    }
    atomicAdd(&h1acc[hfc], a0);
    atomicAdd(&h1acc[HFCc + hfc], a1);
}

__global__ void head_kernel(const float* __restrict__ h1acc, const float* __restrict__ l1b,
                            const float* __restrict__ w2, const float* __restrict__ b2,
                            float* __restrict__ out) {
    __shared__ float sh[HFCc];
    __shared__ float slog[NCc];
    __shared__ float s_lse;
    int tid = threadIdx.x;
    for (int b = 0; b < BSz; ++b) {
        float v = h1acc[b * HFCc + tid] + l1b[tid];
        v = v > 0.f ? v : expm1f(v);
        sh[tid] = v;
        __syncthreads();
        if (tid < NCc) {
            float s = b2[tid];
            for (int i = 0; i < HFCc; ++i) s += sh[i] * w2[i * NCc + tid];
            slog[tid] = s;
        }
        __syncthreads();
        if (tid == 0) {
            float m = slog[0];
            for (int c = 1; c < NCc; ++c) m = fmaxf(m, slog[c]);
            float se = 0.f;
            for (int c = 0; c < NCc; ++c) se += expf(slog[c] - m);
            s_lse = m + logf(se);
        }
        __syncthreads();
        if (tid < NCc) out[b * NCc + tid] = slog[tid] - s_lse;
        __syncthreads();
    }
}

extern "C" void kernel_launch(void* const* d_in, const int* in_sizes, int n_in,
                              void* d_out, int out_size, void* d_ws, size_t ws_size,
                              hipStream_t stream) {
    const float* x      = (const float*)d_in[0];
    const int*   ei     = (const int*)d_in[2];
    const float* pseudo = (const float*)d_in[3];
    const float* g1     = (const float*)d_in[4];
    const float* mu1    = (const float*)d_in[5];
    const float* sigma1 = (const float*)d_in[6];
    const float* root1  = (const float*)d_in[7];
    const float* b1     = (const float*)d_in[8];
    const float* gs     = (const float*)d_in[9];
    const float* mus    = (const float*)d_in[10];
    const float* sigmas = (const float*)d_in[11];
    const float* roots  = (const float*)d_in[12];
    const float* bs_p   = (const float*)d_in[13];
    const float* fc_w   = (const float*)d_in[14];
    const float* fc_b   = (const float*)d_in[15];
    const float* lin1_w = (const float*)d_in[16];
    const float* lin1_b = (const float*)d_in[17];
    const float* lin2_w = (const float*)d_in[18];
    const float* lin2_b = (const float*)d_in[19];
    float* out = (float*)d_out;

    const int* src = ei;
    const int* dst = ei + Ee;

    auto alignup = [](size_t v) { return (v + 255) & ~(size_t)255; };
    char* ws = (char*)d_ws;
    size_t off = 0;
    float*    node    = (float*)(ws + off);    off += alignup((size_t)BSz * Nn * 4);
    float*    h1acc   = (float*)(ws + off);    off += alignup((size_t)BSz * HFCc * 4);
    int*      offs    = (int*)(ws + off);      off += alignup((size_t)(Nn + 1) * 4);
    int*      cursor  = (int*)(ws + off);      off += alignup((size_t)Nn * 4);
    int*      loc     = (int*)(ws + off);      off += alignup((size_t)Nn * 4);
    int*      bsum    = (int*)(ws + off);      off += alignup((size_t)64 * 4);
    int*      csr_src = (int*)(ws + off);      off += alignup((size_t)Ee * 4);
    float2*   csr_ps  = (float2*)(ws + off);   off += alignup((size_t)Ee * 8);
    uint2*    hkp     = (uint2*)(ws + off);    off += alignup((size_t)Nn * 64 * 8);
    float*    hA      = (float*)(ws + off);    off += alignup((size_t)BSz * Nn * 64 * 4);
    float*    hB      = (float*)(ws + off);    off += alignup((size_t)BSz * Nn * 64 * 4);
    unsigned* msg     = (unsigned*)(ws + off); off += alignup((size_t)Ee * 64 * 4);
    (void)ws_size; (void)in_sizes; (void)n_in; (void)out_size;

    hipMemsetAsync(cursor, 0, (size_t)Nn * 4, stream);
    hipMemsetAsync(h1acc, 0, (size_t)BSz * HFCc * 4, stream);

    count_kernel<<<(Ee + 255) / 256, 256, 0, stream>>>(dst, cursor);
    scan_local<<<NBLK, 256, 0, stream>>>(cursor, loc, bsum);
    scan_tops<<<1, 64, 0, stream>>>(bsum);
    scan_fix<<<NBLK, 256, 0, stream>>>(loc, bsum, offs, cursor);
    fill_kernel<<<(Ee + 255) / 256, 256, 0, stream>>>(src, dst, pseudo, cursor, csr_src, csr_ps);

    const float* prev = x;
    float* hnxt = hA;
    float* hother = hB;
    int tgrid = (Nn + 3) / 4;
    int sgrid = (Nn + 15) / 16;
    for (int l = 0; l < Ll; ++l) {
        const float* g  = (l == 0) ? g1     : gs     + (size_t)(l - 1) * Hh * 128;
        const float* rt = (l == 0) ? root1  : roots  + (size_t)(l - 1) * Hh * Hh;
        const float* bb = (l == 0) ? b1     : bs_p   + (size_t)(l - 1) * Hh;
        const float* mu = (l == 0) ? mu1    : mus    + (size_t)(l - 1) * 4;
        const float* sg = (l == 0) ? sigma1 : sigmas + (size_t)(l - 1) * 4;

        if (l == 0)
            transform_pack<F_INc><<<tgrid, 256, 0, stream>>>(prev, g, hkp);
        else
            transform_pack<Hh><<<tgrid, 256, 0, stream>>>(prev, g, hkp);

        expand_kernel<<<XWAVES / 4, 256, 0, stream>>>(hkp, csr_src, csr_ps, mu, sg, msg);

        if (l == 0)
            seg_combine<F_INc><<<sgrid, 1024, 0, stream>>>(msg, offs, prev, rt, bb, fc_w,
                                                           l, hnxt, node);
        else
            seg_combine<Hh><<<sgrid, 1024, 0, stream>>>(msg, offs, prev, rt, bb, fc_w,
                                                        l, hnxt, node);

        prev = hnxt;
        float* tmp = hnxt; hnxt = hother; hother = tmp;
    }

    lin1_kernel<<<(Nn + 63) / 64, 256, 0, stream>>>(node, lin1_w, fc_b, h1acc);
    head_kernel<<<1, HFCc, 0, stream>>>(h1acc, lin1_b, lin2_w, lin2_b, out);
}

// Round 8
// 285.798 us; speedup vs baseline: 1.4621x; 1.4621x over previous
//
#include <hip/hip_runtime.h>
#include <hip/hip_bf16.h>

#define BSz 2
#define Nn 15135
#define Ee 242160
#define F_INc 8
#define Hh 64
#define Ll 4
#define HFCc 256
#define NCc 10
#define EPSg 1e-15f
#define NBLK ((Nn + 255) / 256)   // 60 scan blocks

__device__ __forceinline__ float uf(unsigned u) { return __uint_as_float(u); }
__device__ __forceinline__ unsigned short bs16(float f) {
    unsigned b = __float_as_uint(f);
    return (unsigned short)((b + 0x7FFFu + ((b >> 16) & 1u)) >> 16);
}
__device__ __forceinline__ unsigned packbf(float a, float b) {
    return (unsigned)bs16(a) | ((unsigned)bs16(b) << 16);
}

// ---- CSR build ----------------------------------------------------------

__global__ void count_kernel(const int* __restrict__ dst, int* __restrict__ cnt) {
    int e = blockIdx.x * blockDim.x + threadIdx.x;
    if (e < Ee) atomicAdd(&cnt[dst[e]], 1);
}

__global__ void scan_local(const int* __restrict__ cnt, int* __restrict__ loc,
                           int* __restrict__ bsum) {
    int tid = threadIdx.x, lane = tid & 63, w = tid >> 6;
    int i = blockIdx.x * 256 + tid;
    __shared__ int ws[4];
    int v = (i < Nn) ? cnt[i] : 0;
    int incl = v;
#pragma unroll
    for (int d = 1; d < 64; d <<= 1) {
        int t = __shfl_up(incl, d, 64);
        if (lane >= d) incl += t;
    }
    if (lane == 63) ws[w] = incl;
    __syncthreads();
    int pre = 0;
    for (int ww = 0; ww < w; ++ww) pre += ws[ww];
    if (i < Nn) loc[i] = pre + incl - v;
    if (tid == 255) bsum[blockIdx.x] = pre + incl;
}

__global__ void scan_tops(int* __restrict__ bsum) {
    int lane = threadIdx.x;
    int v = (lane < NBLK) ? bsum[lane] : 0;
    int incl = v;
#pragma unroll
    for (int d = 1; d < 64; d <<= 1) {
        int t = __shfl_up(incl, d, 64);
        if (lane >= d) incl += t;
    }
    if (lane < NBLK) bsum[lane] = incl - v;
}

__global__ void scan_fix(const int* __restrict__ loc, const int* __restrict__ bsum,
                         int* __restrict__ offs, int* __restrict__ cursor) {
    int i = blockIdx.x * 256 + threadIdx.x;
    if (i < Nn) {
        int o = loc[i] + bsum[blockIdx.x];
        offs[i] = o;
        cursor[i] = o;
    }
    if (i == 0) offs[Nn] = Ee;
}

// fill CSR + per-layer gauss arrays gauss[l*E + p] (contiguous per layer)
__global__ void fill_kernel(const int* __restrict__ src, const int* __restrict__ dst,
                            const float* __restrict__ pseudo, int* __restrict__ cursor,
                            int* __restrict__ csr_src, float2* __restrict__ gauss,
                            const float* __restrict__ mu1, const float* __restrict__ sigma1,
                            const float* __restrict__ mus, const float* __restrict__ sigmas) {
    int e = blockIdx.x * blockDim.x + threadIdx.x;
    if (e >= Ee) return;
    int p = atomicAdd(&cursor[dst[e]], 1);
    csr_src[p] = src[e];
    float2 ps = ((const float2*)pseudo)[e];
#pragma unroll
    for (int l = 0; l < Ll; ++l) {
        const float* mu = (l == 0) ? mu1 : mus + (l - 1) * 4;
        const float* sg = (l == 0) ? sigma1 : sigmas + (l - 1) * 4;
        float d00 = ps.x - mu[0], d01 = ps.y - mu[1];
        float d10 = ps.x - mu[2], d11 = ps.y - mu[3];
        float i00 = 1.f / (EPSg + sg[0] * sg[0]);
        float i01 = 1.f / (EPSg + sg[1] * sg[1]);
        float i10 = 1.f / (EPSg + sg[2] * sg[2]);
        float i11 = 1.f / (EPSg + sg[3] * sg[3]);
        float g0 = expf(-0.5f * (d00 * d00 * i00 + d01 * d01 * i01));
        float g1 = expf(-0.5f * (d10 * d10 * i10 + d11 * d11 * i11));
        gauss[(size_t)l * Ee + p] = make_float2(g0, g1);
    }
}

// ---- transform: hkp[n][h] = packed msgs, rootp[n][h] = {prev@root+b}_b0,b1
template<int F>
__global__ void transform_pack(const float* __restrict__ in, const float* __restrict__ g,
                               const float* __restrict__ root, const float* __restrict__ bias,
                               uint2* __restrict__ hkp, float2* __restrict__ rootp) {
    int tid = threadIdx.x;
    int h = tid & 63;
    int r = tid >> 6;
    int n0 = blockIdx.x * 4;
    int n = n0 + r;
    __shared__ float s_in[4][2][F];
    for (int idx = tid; idx < 4 * 2 * F; idx += 256) {
        int rr = idx / (2 * F);
        int bb = (idx / F) & 1;
        int ff = idx % F;
        int gn = n0 + rr;
        s_in[rr][bb][ff] = (gn < Nn) ? in[((size_t)bb * Nn + gn) * F + ff] : 0.f;
    }
    __syncthreads();
    if (n >= Nn) return;
    float bv = bias[h];
    float a00 = 0.f, a01 = 0.f, a10 = 0.f, a11 = 0.f;  // a{batch}{k}
    float r0 = bv, r1 = bv;
#pragma unroll
    for (int f = 0; f < F; ++f) {
        float G0 = g[f * 128 + h];
        float G1 = g[f * 128 + 64 + h];
        float Rv = root[f * 64 + h];
        float v0 = s_in[r][0][f];
        float v1 = s_in[r][1][f];
        a00 = fmaf(v0, G0, a00);
        a01 = fmaf(v0, G1, a01);
        r0  = fmaf(v0, Rv, r0);
        a10 = fmaf(v1, G0, a10);
        a11 = fmaf(v1, G1, a11);
        r1  = fmaf(v1, Rv, r1);
    }
    hkp[(size_t)n * 64 + h] = make_uint2(packbf(a00, a10), packbf(a01, a11));
    rootp[(size_t)n * 64 + h] = make_float2(r0, r1);
}

// ---- gather + combine: one wave per node, trivial epilogue ---------------
template<int F>
__global__ void gather_combine(const uint2* __restrict__ hkp, const int* __restrict__ offs,
                               const int* __restrict__ csr_src, const float2* __restrict__ gauss,
                               const float2* __restrict__ rootp, const float* __restrict__ fc_w,
                               int l, float* __restrict__ hout, float* __restrict__ node) {
    int tid = threadIdx.x;
    int lane = tid & 63;
    int n = blockIdx.x * 4 + (tid >> 6);
    if (n >= Nn) return;
    int s0 = offs[n], s1 = offs[n + 1];
    float acc0 = 0.f, acc1 = 0.f;
    int p = s0;
    for (; p + 3 < s1; p += 4) {
        int sa = csr_src[p], sb = csr_src[p + 1], sc = csr_src[p + 2], sd = csr_src[p + 3];
        float2 ga = gauss[p], gb = gauss[p + 1], gc = gauss[p + 2], gd = gauss[p + 3];
        uint2 ua = hkp[(size_t)sa * 64 + lane];
        uint2 ub = hkp[(size_t)sb * 64 + lane];
        uint2 uc = hkp[(size_t)sc * 64 + lane];
        uint2 ud = hkp[(size_t)sd * 64 + lane];
        acc0 += ga.x * uf(ua.x << 16) + ga.y * uf(ua.y << 16);
        acc1 += ga.x * uf(ua.x & 0xFFFF0000u) + ga.y * uf(ua.y & 0xFFFF0000u);
        acc0 += gb.x * uf(ub.x << 16) + gb.y * uf(ub.y << 16);
        acc1 += gb.x * uf(ub.x & 0xFFFF0000u) + gb.y * uf(ub.y & 0xFFFF0000u);
        acc0 += gc.x * uf(uc.x << 16) + gc.y * uf(uc.y << 16);
        acc1 += gc.x * uf(uc.x & 0xFFFF0000u) + gc.y * uf(uc.y & 0xFFFF0000u);
        acc0 += gd.x * uf(ud.x << 16) + gd.y * uf(ud.y << 16);
        acc1 += gd.x * uf(ud.x & 0xFFFF0000u) + gd.y * uf(ud.y & 0xFFFF0000u);
    }
    for (; p < s1; ++p) {
        int sa = csr_src[p];
        float2 ga = gauss[p];
        uint2 ua = hkp[(size_t)sa * 64 + lane];
        acc0 += ga.x * uf(ua.x << 16) + ga.y * uf(ua.y << 16);
        acc1 += ga.x * uf(ua.x & 0xFFFF0000u) + ga.y * uf(ua.y & 0xFFFF0000u);
    }
    float dg = (float)(s1 - s0);
    if (dg < 1.f) dg = 1.f;
    float inv = 1.f / dg;
    float2 rp = rootp[(size_t)n * 64 + lane];
    float val0 = fmaf(acc0, inv, rp.x);
    float val1 = fmaf(acc1, inv, rp.y);
    val0 = val0 > 0.f ? val0 : expm1f(val0);
    val1 = val1 > 0.f ? val1 : expm1f(val1);
    hout[(size_t)n * 64 + lane] = val0;
    hout[(size_t)(Nn + n) * 64 + lane] = val1;
    float fw = fc_w[lane * Ll + l];
    float r0 = val0 * fw, r1 = val1 * fw;
#pragma unroll
    for (int off = 32; off; off >>= 1) {
        r0 += __shfl_down(r0, off, 64);
        r1 += __shfl_down(r1, off, 64);
    }
    if (lane == 0) {
        if (l == 0) { node[n] = r0; node[Nn + n] = r1; }
        else        { node[n] += r0; node[Nn + n] += r1; }
    }
}

// ---- head ----------------------------------------------------------------

__global__ void lin1_kernel(const float* __restrict__ node, const float* __restrict__ w,
                            const float* __restrict__ fcb, float* __restrict__ h1acc) {
    int hfc = threadIdx.x;
    int n0 = blockIdx.x * 64;
    int nend = n0 + 64 < Nn ? n0 + 64 : Nn;
    float fb = fcb[0];
    float a0 = 0.f, a1 = 0.f;
    for (int n = n0; n < nend; ++n) {
        float wv = w[(size_t)n * HFCc + hfc];
        a0 += (node[n] + fb) * wv;
        a1 += (node[Nn + n] + fb) * wv;
    }
    atomicAdd(&h1acc[hfc], a0);
    atomicAdd(&h1acc[HFCc + hfc], a1);
}

__global__ void head_kernel(const float* __restrict__ h1acc, const float* __restrict__ l1b,
                            const float* __restrict__ w2, const float* __restrict__ b2,
                            float* __restrict__ out) {
    __shared__ float sh[HFCc];
    __shared__ float slog[NCc];
    __shared__ float s_lse;
    int tid = threadIdx.x;
    for (int b = 0; b < BSz; ++b) {
        float v = h1acc[b * HFCc + tid] + l1b[tid];
        v = v > 0.f ? v : expm1f(v);
        sh[tid] = v;
        __syncthreads();
        if (tid < NCc) {
            float s = b2[tid];
            for (int i = 0; i < HFCc; ++i) s += sh[i] * w2[i * NCc + tid];
            slog[tid] = s;
        }
        __syncthreads();
        if (tid == 0) {
            float m = slog[0];
            for (int c = 1; c < NCc; ++c) m = fmaxf(m, slog[c]);
            float se = 0.f;
            for (int c = 0; c < NCc; ++c) se += expf(slog[c] - m);
            s_lse = m + logf(se);
        }
        __syncthreads();
        if (tid < NCc) out[b * NCc + tid] = slog[tid] - s_lse;
        __syncthreads();
    }
}

extern "C" void kernel_launch(void* const* d_in, const int* in_sizes, int n_in,
                              void* d_out, int out_size, void* d_ws, size_t ws_size,
                              hipStream_t stream) {
    const float* x      = (const float*)d_in[0];
    const int*   ei     = (const int*)d_in[2];
    const float* pseudo = (const float*)d_in[3];
    const float* g1     = (const float*)d_in[4];
    const float* mu1    = (const float*)d_in[5];
    const float* sigma1 = (const float*)d_in[6];
    const float* root1  = (const float*)d_in[7];
    const float* b1     = (const float*)d_in[8];
    const float* gs     = (const float*)d_in[9];
    const float* mus    = (const float*)d_in[10];
    const float* sigmas = (const float*)d_in[11];
    const float* roots  = (const float*)d_in[12];
    const float* bs_p   = (const float*)d_in[13];
    const float* fc_w   = (const float*)d_in[14];
    const float* fc_b   = (const float*)d_in[15];
    const float* lin1_w = (const float*)d_in[16];
    const float* lin1_b = (const float*)d_in[17];
    const float* lin2_w = (const float*)d_in[18];
    const float* lin2_b = (const float*)d_in[19];
    float* out = (float*)d_out;

    const int* src = ei;
    const int* dst = ei + Ee;

    auto alignup = [](size_t v) { return (v + 255) & ~(size_t)255; };
    char* ws = (char*)d_ws;
    size_t off = 0;
    float*  node    = (float*)(ws + off);   off += alignup((size_t)BSz * Nn * 4);
    float*  h1acc   = (float*)(ws + off);   off += alignup((size_t)BSz * HFCc * 4);
    int*    offs    = (int*)(ws + off);     off += alignup((size_t)(Nn + 1) * 4);
    int*    cursor  = (int*)(ws + off);     off += alignup((size_t)Nn * 4);
    int*    loc     = (int*)(ws + off);     off += alignup((size_t)Nn * 4);
    int*    bsum    = (int*)(ws + off);     off += alignup((size_t)64 * 4);
    int*    csr_src = (int*)(ws + off);     off += alignup((size_t)Ee * 4);
    float2* gauss   = (float2*)(ws + off);  off += alignup((size_t)Ll * Ee * 8);
    uint2*  hkp     = (uint2*)(ws + off);   off += alignup((size_t)Nn * 64 * 8);
    float2* rootp   = (float2*)(ws + off);  off += alignup((size_t)Nn * 64 * 8);
    float*  hA      = (float*)(ws + off);   off += alignup((size_t)BSz * Nn * 64 * 4);
    float*  hB      = (float*)(ws + off);   off += alignup((size_t)BSz * Nn * 64 * 4);
    (void)ws_size; (void)in_sizes; (void)n_in; (void)out_size;

    hipMemsetAsync(cursor, 0, (size_t)Nn * 4, stream);
    hipMemsetAsync(h1acc, 0, (size_t)BSz * HFCc * 4, stream);

    count_kernel<<<(Ee + 255) / 256, 256, 0, stream>>>(dst, cursor);
    scan_local<<<NBLK, 256, 0, stream>>>(cursor, loc, bsum);
    scan_tops<<<1, 64, 0, stream>>>(bsum);
    scan_fix<<<NBLK, 256, 0, stream>>>(loc, bsum, offs, cursor);
    fill_kernel<<<(Ee + 255) / 256, 256, 0, stream>>>(src, dst, pseudo, cursor, csr_src, gauss,
                                                      mu1, sigma1, mus, sigmas);

    const float* prev = x;
    float* hnxt = hA;
    float* hother = hB;
    int ngrid = (Nn + 3) / 4;
    for (int l = 0; l < Ll; ++l) {
        const float* g  = (l == 0) ? g1    : gs    + (size_t)(l - 1) * Hh * 128;
        const float* rt = (l == 0) ? root1 : roots + (size_t)(l - 1) * Hh * Hh;
        const float* bb = (l == 0) ? b1    : bs_p  + (size_t)(l - 1) * Hh;

        if (l == 0)
            transform_pack<F_INc><<<ngrid, 256, 0, stream>>>(prev, g, rt, bb, hkp, rootp);
        else
            transform_pack<Hh><<<ngrid, 256, 0, stream>>>(prev, g, rt, bb, hkp, rootp);

        if (l == 0)
            gather_combine<F_INc><<<ngrid, 256, 0, stream>>>(hkp, offs, csr_src,
                gauss + (size_t)l * Ee, rootp, fc_w, l, hnxt, node);
        else
            gather_combine<Hh><<<ngrid, 256, 0, stream>>>(hkp, offs, csr_src,
                gauss + (size_t)l * Ee, rootp, fc_w, l, hnxt, node);

        prev = hnxt;
        float* tmp = hnxt; hnxt = hother; hother = tmp;
    }

    lin1_kernel<<<(Nn + 63) / 64, 256, 0, stream>>>(node, lin1_w, fc_b, h1acc);
    head_kernel<<<1, HFCc, 0, stream>>>(h1acc, lin1_b, lin2_w, lin2_b, out);
}

// Round 9
// 281.196 us; speedup vs baseline: 1.4861x; 1.0164x over previous
//
#include <hip/hip_runtime.h>
#include <hip/hip_bf16.h>

#define BSz 2
#define Nn 15135
#define Ee 242160
#define F_INc 8
#define Hh 64
#define Ll 4
#define HFCc 256
#define NCc 10
#define EPSg 1e-15f
#define NBLK ((Nn + 255) / 256)   // 60 scan blocks

__device__ __forceinline__ float uf(unsigned u) { return __uint_as_float(u); }
__device__ __forceinline__ unsigned short bs16(float f) {
    unsigned b = __float_as_uint(f);
    return (unsigned short)((b + 0x7FFFu + ((b >> 16) & 1u)) >> 16);
}
__device__ __forceinline__ unsigned packbf(float a, float b) {
    return (unsigned)bs16(a) | ((unsigned)bs16(b) << 16);
}

// ---- init (replaces pathological hipMemsetAsync fills) -------------------

__global__ void zero_kernel(int* __restrict__ cursor, float* __restrict__ h1acc) {
    int i = blockIdx.x * 256 + threadIdx.x;
    if (i < Nn) cursor[i] = 0;
    if (i < BSz * HFCc) h1acc[i] = 0.f;
}

// ---- CSR build ----------------------------------------------------------

__global__ void count_kernel(const int* __restrict__ dst, int* __restrict__ cnt) {
    int e = blockIdx.x * blockDim.x + threadIdx.x;
    if (e < Ee) atomicAdd(&cnt[dst[e]], 1);
}

__global__ void scan_local(const int* __restrict__ cnt, int* __restrict__ loc,
                           int* __restrict__ bsum) {
    int tid = threadIdx.x, lane = tid & 63, w = tid >> 6;
    int i = blockIdx.x * 256 + tid;
    __shared__ int ws[4];
    int v = (i < Nn) ? cnt[i] : 0;
    int incl = v;
#pragma unroll
    for (int d = 1; d < 64; d <<= 1) {
        int t = __shfl_up(incl, d, 64);
        if (lane >= d) incl += t;
    }
    if (lane == 63) ws[w] = incl;
    __syncthreads();
    int pre = 0;
    for (int ww = 0; ww < w; ++ww) pre += ws[ww];
    if (i < Nn) loc[i] = pre + incl - v;
    if (tid == 255) bsum[blockIdx.x] = pre + incl;
}

__global__ void scan_tops(int* __restrict__ bsum) {
    int lane = threadIdx.x;
    int v = (lane < NBLK) ? bsum[lane] : 0;
    int incl = v;
#pragma unroll
    for (int d = 1; d < 64; d <<= 1) {
        int t = __shfl_up(incl, d, 64);
        if (lane >= d) incl += t;
    }
    if (lane < NBLK) bsum[lane] = incl - v;
}

__global__ void scan_fix(const int* __restrict__ loc, const int* __restrict__ bsum,
                         int* __restrict__ offs, int* __restrict__ cursor) {
    int i = blockIdx.x * 256 + threadIdx.x;
    if (i < Nn) {
        int o = loc[i] + bsum[blockIdx.x];
        offs[i] = o;
        cursor[i] = o;
    }
    if (i == 0) offs[Nn] = Ee;
}

// fill CSR + per-layer gauss arrays gauss[l*E + p] (contiguous per layer)
__global__ void fill_kernel(const int* __restrict__ src, const int* __restrict__ dst,
                            const float* __restrict__ pseudo, int* __restrict__ cursor,
                            int* __restrict__ csr_src, float2* __restrict__ gauss,
                            const float* __restrict__ mu1, const float* __restrict__ sigma1,
                            const float* __restrict__ mus, const float* __restrict__ sigmas) {
    int e = blockIdx.x * blockDim.x + threadIdx.x;
    if (e >= Ee) return;
    int p = atomicAdd(&cursor[dst[e]], 1);
    csr_src[p] = src[e];
    float2 ps = ((const float2*)pseudo)[e];
#pragma unroll
    for (int l = 0; l < Ll; ++l) {
        const float* mu = (l == 0) ? mu1 : mus + (l - 1) * 4;
        const float* sg = (l == 0) ? sigma1 : sigmas + (l - 1) * 4;
        float d00 = ps.x - mu[0], d01 = ps.y - mu[1];
        float d10 = ps.x - mu[2], d11 = ps.y - mu[3];
        float i00 = 1.f / (EPSg + sg[0] * sg[0]);
        float i01 = 1.f / (EPSg + sg[1] * sg[1]);
        float i10 = 1.f / (EPSg + sg[2] * sg[2]);
        float i11 = 1.f / (EPSg + sg[3] * sg[3]);
        float g0 = expf(-0.5f * (d00 * d00 * i00 + d01 * d01 * i01));
        float g1 = expf(-0.5f * (d10 * d10 * i10 + d11 * d11 * i11));
        gauss[(size_t)l * Ee + p] = make_float2(g0, g1);
    }
}

// ---- transform: hkp[n][h] = packed msgs, rootp[n][h] = {prev@root+b}_b0,b1
template<int F>
__global__ void transform_pack(const float* __restrict__ in, const float* __restrict__ g,
                               const float* __restrict__ root, const float* __restrict__ bias,
                               uint2* __restrict__ hkp, float2* __restrict__ rootp) {
    int tid = threadIdx.x;
    int h = tid & 63;
    int r = tid >> 6;
    int n0 = blockIdx.x * 4;
    int n = n0 + r;
    __shared__ float s_in[4][2][F];
    for (int idx = tid; idx < 4 * 2 * F; idx += 256) {
        int rr = idx / (2 * F);
        int bb = (idx / F) & 1;
        int ff = idx % F;
        int gn = n0 + rr;
        s_in[rr][bb][ff] = (gn < Nn) ? in[((size_t)bb * Nn + gn) * F + ff] : 0.f;
    }
    __syncthreads();
    if (n >= Nn) return;
    float bv = bias[h];
    float a00 = 0.f, a01 = 0.f, a10 = 0.f, a11 = 0.f;  // a{batch}{k}
    float r0 = bv, r1 = bv;
#pragma unroll
    for (int f = 0; f < F; ++f) {
        float G0 = g[f * 128 + h];
        float G1 = g[f * 128 + 64 + h];
        float Rv = root[f * 64 + h];
        float v0 = s_in[r][0][f];
        float v1 = s_in[r][1][f];
        a00 = fmaf(v0, G0, a00);
        a01 = fmaf(v0, G1, a01);
        r0  = fmaf(v0, Rv, r0);
        a10 = fmaf(v1, G0, a10);
        a11 = fmaf(v1, G1, a11);
        r1  = fmaf(v1, Rv, r1);
    }
    hkp[(size_t)n * 64 + h] = make_uint2(packbf(a00, a10), packbf(a01, a11));
    rootp[(size_t)n * 64 + h] = make_float2(r0, r1);
}

// ---- gather + combine: one wave per node, trivial epilogue ---------------
template<int F>
__global__ void gather_combine(const uint2* __restrict__ hkp, const int* __restrict__ offs,
                               const int* __restrict__ csr_src, const float2* __restrict__ gauss,
                               const float2* __restrict__ rootp, const float* __restrict__ fc_w,
                               int l, float* __restrict__ hout, float* __restrict__ node) {
    int tid = threadIdx.x;
    int lane = tid & 63;
    int n = blockIdx.x * 4 + (tid >> 6);
    if (n >= Nn) return;
    int s0 = offs[n], s1 = offs[n + 1];
    float acc0 = 0.f, acc1 = 0.f;
    int p = s0;
    for (; p + 3 < s1; p += 4) {
        int sa = csr_src[p], sb = csr_src[p + 1], sc = csr_src[p + 2], sd = csr_src[p + 3];
        float2 ga = gauss[p], gb = gauss[p + 1], gc = gauss[p + 2], gd = gauss[p + 3];
        uint2 ua = hkp[(size_t)sa * 64 + lane];
        uint2 ub = hkp[(size_t)sb * 64 + lane];
        uint2 uc = hkp[(size_t)sc * 64 + lane];
        uint2 ud = hkp[(size_t)sd * 64 + lane];
        acc0 += ga.x * uf(ua.x << 16) + ga.y * uf(ua.y << 16);
        acc1 += ga.x * uf(ua.x & 0xFFFF0000u) + ga.y * uf(ua.y & 0xFFFF0000u);
        acc0 += gb.x * uf(ub.x << 16) + gb.y * uf(ub.y << 16);
        acc1 += gb.x * uf(ub.x & 0xFFFF0000u) + gb.y * uf(ub.y & 0xFFFF0000u);
        acc0 += gc.x * uf(uc.x << 16) + gc.y * uf(uc.y << 16);
        acc1 += gc.x * uf(uc.x & 0xFFFF0000u) + gc.y * uf(uc.y & 0xFFFF0000u);
        acc0 += gd.x * uf(ud.x << 16) + gd.y * uf(ud.y << 16);
        acc1 += gd.x * uf(ud.x & 0xFFFF0000u) + gd.y * uf(ud.y & 0xFFFF0000u);
    }
    for (; p < s1; ++p) {
        int sa = csr_src[p];
        float2 ga = gauss[p];
        uint2 ua = hkp[(size_t)sa * 64 + lane];
        acc0 += ga.x * uf(ua.x << 16) + ga.y * uf(ua.y << 16);
        acc1 += ga.x * uf(ua.x & 0xFFFF0000u) + ga.y * uf(ua.y & 0xFFFF0000u);
    }
    float dg = (float)(s1 - s0);
    if (dg < 1.f) dg = 1.f;
    float inv = 1.f / dg;
    float2 rp = rootp[(size_t)n * 64 + lane];
    float val0 = fmaf(acc0, inv, rp.x);
    float val1 = fmaf(acc1, inv, rp.y);
    val0 = val0 > 0.f ? val0 : expm1f(val0);
    val1 = val1 > 0.f ? val1 : expm1f(val1);
    hout[(size_t)n * 64 + lane] = val0;
    hout[(size_t)(Nn + n) * 64 + lane] = val1;
    float fw = fc_w[lane * Ll + l];
    float r0 = val0 * fw, r1 = val1 * fw;
#pragma unroll
    for (int off = 32; off; off >>= 1) {
        r0 += __shfl_down(r0, off, 64);
        r1 += __shfl_down(r1, off, 64);
    }
    if (lane == 0) {
        if (l == 0) { node[n] = r0; node[Nn + n] = r1; }
        else        { node[n] += r0; node[Nn + n] += r1; }
    }
}

// ---- head ----------------------------------------------------------------

__global__ void lin1_kernel(const float* __restrict__ node, const float* __restrict__ w,
                            const float* __restrict__ fcb, float* __restrict__ h1acc) {
    int hfc = threadIdx.x;
    int n0 = blockIdx.x * 64;
    int nend = n0 + 64 < Nn ? n0 + 64 : Nn;
    float fb = fcb[0];
    float a0 = 0.f, a1 = 0.f;
    for (int n = n0; n < nend; ++n) {
        float wv = w[(size_t)n * HFCc + hfc];
        a0 += (node[n] + fb) * wv;
        a1 += (node[Nn + n] + fb) * wv;
    }
    atomicAdd(&h1acc[hfc], a0);
    atomicAdd(&h1acc[HFCc + hfc], a1);
}

__global__ void head_kernel(const float* __restrict__ h1acc, const float* __restrict__ l1b,
                            const float* __restrict__ w2, const float* __restrict__ b2,
                            float* __restrict__ out) {
    __shared__ float sh[HFCc];
    __shared__ float slog[NCc];
    __shared__ float s_lse;
    int tid = threadIdx.x;
    for (int b = 0; b < BSz; ++b) {
        float v = h1acc[b * HFCc + tid] + l1b[tid];
        v = v > 0.f ? v : expm1f(v);
        sh[tid] = v;
        __syncthreads();
        if (tid < NCc) {
            float s = b2[tid];
            for (int i = 0; i < HFCc; ++i) s += sh[i] * w2[i * NCc + tid];
            slog[tid] = s;
        }
        __syncthreads();
        if (tid == 0) {
            float m = slog[0];
            for (int c = 1; c < NCc; ++c) m = fmaxf(m, slog[c]);
            float se = 0.f;
            for (int c = 0; c < NCc; ++c) se += expf(slog[c] - m);
            s_lse = m + logf(se);
        }
        __syncthreads();
        if (tid < NCc) out[b * NCc + tid] = slog[tid] - s_lse;
        __syncthreads();
    }
}

extern "C" void kernel_launch(void* const* d_in, const int* in_sizes, int n_in,
                              void* d_out, int out_size, void* d_ws, size_t ws_size,
                              hipStream_t stream) {
    const float* x      = (const float*)d_in[0];
    const int*   ei     = (const int*)d_in[2];
    const float* pseudo = (const float*)d_in[3];
    const float* g1     = (const float*)d_in[4];
    const float* mu1    = (const float*)d_in[5];
    const float* sigma1 = (const float*)d_in[6];
    const float* root1  = (const float*)d_in[7];
    const float* b1     = (const float*)d_in[8];
    const float* gs     = (const float*)d_in[9];
    const float* mus    = (const float*)d_in[10];
    const float* sigmas = (const float*)d_in[11];
    const float* roots  = (const float*)d_in[12];
    const float* bs_p   = (const float*)d_in[13];
    const float* fc_w   = (const float*)d_in[14];
    const float* fc_b   = (const float*)d_in[15];
    const float* lin1_w = (const float*)d_in[16];
    const float* lin1_b = (const float*)d_in[17];
    const float* lin2_w = (const float*)d_in[18];
    const float* lin2_b = (const float*)d_in[19];
    float* out = (float*)d_out;

    const int* src = ei;
    const int* dst = ei + Ee;

    auto alignup = [](size_t v) { return (v + 255) & ~(size_t)255; };
    char* ws = (char*)d_ws;
    size_t off = 0;
    float*  node    = (float*)(ws + off);   off += alignup((size_t)BSz * Nn * 4);
    float*  h1acc   = (float*)(ws + off);   off += alignup((size_t)BSz * HFCc * 4);
    int*    offs    = (int*)(ws + off);     off += alignup((size_t)(Nn + 1) * 4);
    int*    cursor  = (int*)(ws + off);     off += alignup((size_t)Nn * 4);
    int*    loc     = (int*)(ws + off);     off += alignup((size_t)Nn * 4);
    int*    bsum    = (int*)(ws + off);     off += alignup((size_t)64 * 4);
    int*    csr_src = (int*)(ws + off);     off += alignup((size_t)Ee * 4);
    float2* gauss   = (float2*)(ws + off);  off += alignup((size_t)Ll * Ee * 8);
    uint2*  hkp     = (uint2*)(ws + off);   off += alignup((size_t)Nn * 64 * 8);
    float2* rootp   = (float2*)(ws + off);  off += alignup((size_t)Nn * 64 * 8);
    float*  hA      = (float*)(ws + off);   off += alignup((size_t)BSz * Nn * 64 * 4);
    float*  hB      = (float*)(ws + off);   off += alignup((size_t)BSz * Nn * 64 * 4);
    (void)ws_size; (void)in_sizes; (void)n_in; (void)out_size;

    zero_kernel<<<NBLK, 256, 0, stream>>>(cursor, h1acc);

    count_kernel<<<(Ee + 255) / 256, 256, 0, stream>>>(dst, cursor);
    scan_local<<<NBLK, 256, 0, stream>>>(cursor, loc, bsum);
    scan_tops<<<1, 64, 0, stream>>>(bsum);
    scan_fix<<<NBLK, 256, 0, stream>>>(loc, bsum, offs, cursor);
    fill_kernel<<<(Ee + 255) / 256, 256, 0, stream>>>(src, dst, pseudo, cursor, csr_src, gauss,
                                                      mu1, sigma1, mus, sigmas);

    const float* prev = x;
    float* hnxt = hA;
    float* hother = hB;
    int ngrid = (Nn + 3) / 4;
    for (int l = 0; l < Ll; ++l) {
        const float* g  = (l == 0) ? g1    : gs    + (size_t)(l - 1) * Hh * 128;
        const float* rt = (l == 0) ? root1 : roots + (size_t)(l - 1) * Hh * Hh;
        const float* bb = (l == 0) ? b1    : bs_p  + (size_t)(l - 1) * Hh;

        if (l == 0)
            transform_pack<F_INc><<<ngrid, 256, 0, stream>>>(prev, g, rt, bb, hkp, rootp);
        else
            transform_pack<Hh><<<ngrid, 256, 0, stream>>>(prev, g, rt, bb, hkp, rootp);

        if (l == 0)
            gather_combine<F_INc><<<ngrid, 256, 0, stream>>>(hkp, offs, csr_src,
                gauss + (size_t)l * Ee, rootp, fc_w, l, hnxt, node);
        else
            gather_combine<Hh><<<ngrid, 256, 0, stream>>>(hkp, offs, csr_src,
                gauss + (size_t)l * Ee, rootp, fc_w, l, hnxt, node);

        prev = hnxt;
        float* tmp = hnxt; hnxt = hother; hother = tmp;
    }

    lin1_kernel<<<(Nn + 63) / 64, 256, 0, stream>>>(node, lin1_w, fc_b, h1acc);
    head_kernel<<<1, HFCc, 0, stream>>>(h1acc, lin1_b, lin2_w, lin2_b, out);
}